// Round 10
// baseline (475.905 us; speedup 1.0000x reference)
//
#include <hip/hip_runtime.h>
#include <hip/hip_bf16.h>
#include <math.h>

#define Bq 48
#define Sq 512
#define Hq 768
#define Eq 128
#define Lq 16
#define Pq 256
#define NERq 11
#define NER_TOT (Bq*Sq*NERq)   // 270336

typedef __attribute__((ext_vector_type(8))) short s16x8;   // 8 bf16 = 4 VGPR
typedef __attribute__((ext_vector_type(4))) float f32x4;
#define MFMA16(a,b,c) __builtin_amdgcn_mfma_f32_16x16x32_bf16(a,b,c,0,0,0)

// f32 -> bf16 bits, round-to-nearest-even
__device__ __forceinline__ unsigned short f2bf(float f){
  union{float f; unsigned u;} v; v.f=f;
  unsigned r = v.u + 0x7fffu + ((v.u>>16)&1u);
  return (unsigned short)(r>>16);
}
__device__ __forceinline__ float bfu2f(unsigned short h){
  union{unsigned u; float f;} c; c.u = ((unsigned)h)<<16; return c.f;
}
__device__ __forceinline__ s16x8 pack_bf8(float4 lo, float4 hi){
  union { s16x8 v; unsigned short u[8]; } r;
  r.u[0]=f2bf(lo.x); r.u[1]=f2bf(lo.y); r.u[2]=f2bf(lo.z); r.u[3]=f2bf(lo.w);
  r.u[4]=f2bf(hi.x); r.u[5]=f2bf(hi.y); r.u[6]=f2bf(hi.z); r.u[7]=f2bf(hi.w);
  return r.v;
}

// ---------------- prep: transpose weights to bf16 [N][K] ----------------
__global__ __launch_bounds__(256) void k_prep(const float* __restrict__ W1, const float* __restrict__ W2,
      const float* __restrict__ Wg1, const float* __restrict__ Wr1,
      unsigned short* __restrict__ W1t, unsigned short* __restrict__ W2t,
      unsigned short* __restrict__ Wg1t, unsigned short* __restrict__ Wr1t){
  int i = blockIdx.x*256 + threadIdx.x;   // 831488 total = 3248*256
  if (i < 196608){
    int n = i/768, k = i - n*768;
    W1t[i] = f2bf(W1[k*256 + n]);
  } else if (i < 200704){
    int j = i - 196608; int n = j>>8, k = j&255;
    W2t[j] = (n < NERq) ? f2bf(W2[k*NERq + n]) : 0;
  } else if (i < 593920){
    int j = i - 200704; int n = j/768, k = j - n*768;
    Wg1t[j] = f2bf(Wg1[k*512 + n]);
  } else {
    int j = i - 593920; int n = j/928, k = j - n*928;
    Wr1t[j] = f2bf(Wr1[k*256 + n]);
  }
}

// ---------------- NER layer 1: 4-wave blocks, wave = column tile, no LDS ----------------
// grid 768: block computes rows bx*32..+31; wave w covers cols w*64..+63.
__global__ __launch_bounds__(256) void k_ner1(const float* __restrict__ seq, const unsigned short* __restrict__ W1t,
      const float* __restrict__ b1, unsigned short* __restrict__ hid){
  int tid = threadIdx.x, wave = tid>>6, lane = tid&63, m_ = lane&15, kq = lane>>4;
  size_t row0 = (size_t)blockIdx.x*32;
  int n0 = wave*64;
  const float* A0 = seq + (row0 + m_)*Hq + kq*8;
  const float* A1 = A0 + 16*Hq;
  const unsigned short* Wb = W1t + (size_t)(n0 + m_)*768 + kq*8;
  const f32x4 z = {0.f,0.f,0.f,0.f};
  f32x4 acc[2][4];
  #pragma unroll
  for (int rt=0;rt<2;rt++)
    #pragma unroll
    for (int ct=0;ct<4;ct++) acc[rt][ct]=z;
  for (int k0=0; k0<768; k0+=32){
    float4 l0 = *(const float4*)(A0 + k0);
    float4 h0 = *(const float4*)(A0 + k0 + 4);
    float4 l1 = *(const float4*)(A1 + k0);
    float4 h1v = *(const float4*)(A1 + k0 + 4);
    s16x8 b0 = *(const s16x8*)(Wb + k0);
    s16x8 b1v = *(const s16x8*)(Wb + 16*768 + k0);
    s16x8 b2v = *(const s16x8*)(Wb + 32*768 + k0);
    s16x8 b3v = *(const s16x8*)(Wb + 48*768 + k0);
    s16x8 a0 = pack_bf8(l0,h0);
    s16x8 a1 = pack_bf8(l1,h1v);
    acc[0][0]=MFMA16(a0,b0 ,acc[0][0]); acc[1][0]=MFMA16(a1,b0 ,acc[1][0]);
    acc[0][1]=MFMA16(a0,b1v,acc[0][1]); acc[1][1]=MFMA16(a1,b1v,acc[1][1]);
    acc[0][2]=MFMA16(a0,b2v,acc[0][2]); acc[1][2]=MFMA16(a1,b2v,acc[1][2]);
    acc[0][3]=MFMA16(a0,b3v,acc[0][3]); acc[1][3]=MFMA16(a1,b3v,acc[1][3]);
  }
  #pragma unroll
  for (int ct=0;ct<4;ct++){
    int col = n0 + ct*16 + m_;
    float bb = b1[col];
    #pragma unroll
    for (int rt=0;rt<2;rt++)
      #pragma unroll
      for (int rg=0;rg<4;rg++){
        int row = rt*16 + kq*4 + rg;
        hid[(row0+row)*256 + col] = f2bf(fmaxf(acc[rt][ct][rg] + bb, 0.f));
      }
  }
}

// ---------------- NER layer 2: hidden(bf16) @ W2t, K=256; 4-wave blocks ----------------
__global__ __launch_bounds__(256) void k_ner2(const unsigned short* __restrict__ hid,
      const unsigned short* __restrict__ W2t, const float* __restrict__ b2, float* __restrict__ out){
  int tid = threadIdx.x, wave = tid>>6, lane = tid&63, m_ = lane&15, kq = lane>>4;
  size_t row0 = (size_t)blockIdx.x*64 + wave*16;   // 384 blocks
  f32x4 a2 = {0.f,0.f,0.f,0.f};
  for (int k0=0;k0<256;k0+=32){
    s16x8 a = *(const s16x8*)&hid[(row0+m_)*256 + k0 + kq*8];
    s16x8 b = *(const s16x8*)&W2t[m_*256 + k0 + kq*8];
    a2 = MFMA16(a,b,a2);
  }
  if (m_ < NERq){
    float bb = b2[m_];
    #pragma unroll
    for (int rg=0;rg<4;rg++)
      out[(row0+kq*4+rg)*NERq + m_] = a2[rg] + bb;
  }
}

// ---------------- span pooling: register-staged tokens ----------------
__global__ __launch_bounds__(256) void k_span(const float* __restrict__ seq, const int* __restrict__ sstart,
      const int* __restrict__ slen, const int* __restrict__ etype, const float* __restrict__ type_emb,
      float* __restrict__ x, float* __restrict__ inv){
  __shared__ float red16[4][16];
  __shared__ float wv[16];
  __shared__ float redn[4];
  int be = blockIdx.x;
  int b = be >> 7;
  int tid = threadIdx.x;
  int wave = tid>>6, lane = tid&63;
  int st = sstart[be], ln = slen[be];
  int cnt = ln + 1;                // mask = pos <= len; rows >= cnt have weight exactly 0
  const float* base = seq + ((size_t)b*Sq + st)*Hq;
  float tokr[16][3];
  #pragma unroll
  for (int l=0;l<16;l++){
    if (l < cnt){
      tokr[l][0] = base[l*768 + tid];
      tokr[l][1] = base[l*768 + tid + 256];
      tokr[l][2] = base[l*768 + tid + 512];
    } else {
      tokr[l][0]=0.f; tokr[l][1]=0.f; tokr[l][2]=0.f;
    }
  }
  float meanr[3];
  #pragma unroll
  for (int c=0;c<3;c++){
    float s=0.f;
    #pragma unroll
    for (int l=0;l<16;l++) if (l < cnt) s += tokr[l][c];
    meanr[c] = s/(float)cnt;
  }
  #pragma unroll
  for (int l=0;l<16;l++){
    if (l < cnt){
      float p = tokr[l][0]*meanr[0] + tokr[l][1]*meanr[1] + tokr[l][2]*meanr[2];
      #pragma unroll
      for (int off=32; off; off>>=1) p += __shfl_down(p, off, 64);
      if (lane==0) red16[wave][l] = p;
    }
  }
  __syncthreads();
  if (tid==0){
    float sc[16];
    for (int l=0;l<cnt;l++) sc[l] = red16[0][l]+red16[1][l]+red16[2][l]+red16[3][l];
    float m=-1e30f;
    for (int l=0;l<cnt;l++) m = fmaxf(m, sc[l]);
    float ssum=0.f;
    float e[16];
    for (int l=0;l<16;l++){
      e[l] = (l<cnt) ? expf(sc[l]-m) : 0.f;
      ssum += e[l];
    }
    float rs = 1.f/ssum;
    for (int l=0;l<16;l++) wv[l] = e[l]*rs;
  }
  __syncthreads();
  const float* te = type_emb + (size_t)etype[be]*Hq;
  float nrm = 0.f;
  #pragma unroll
  for (int c=0;c<3;c++){
    int h = tid + c*256;
    float p=0.f;
    #pragma unroll
    for (int l=0;l<16;l++) if (l < cnt) p += wv[l]*tokr[l][c];
    float xv = p + te[h];
    x[(size_t)be*Hq + h] = xv;
    nrm += xv*xv;
  }
  #pragma unroll
  for (int off=32; off; off>>=1) nrm += __shfl_down(nrm, off, 64);
  if (lane==0) redn[wave]=nrm;
  __syncthreads();
  if (tid==0){
    float t = redn[0]+redn[1]+redn[2]+redn[3];
    inv[be] = 1.f/fmaxf(sqrtf(t), 1e-12f);
  }
}

// ---------------- sim: 32x32 tiles, K-chunks of 128, 768 blocks ----------------
__global__ __launch_bounds__(256) void k_sim(const float* __restrict__ x, const float* __restrict__ inv,
                                             float* __restrict__ sim){
  __shared__ float As[128][33];
  __shared__ float Bs[128][33];
  int b = blockIdx.z;
  int i0 = blockIdx.y*32, j0 = blockIdx.x*32;
  int tid = threadIdx.x;
  int ty = tid>>4, tx = tid&15;
  float acc[2][2] = {{0.f,0.f},{0.f,0.f}};
  const float* xb = x + (size_t)b*Eq*Hq;
  for (int k0=0;k0<768;k0+=128){
    for (int idx=tid; idx<1024; idx+=256){
      int kq = idx&31, r = idx>>5;
      float4 va = *(const float4*)&xb[(size_t)(i0+r)*768 + k0 + kq*4];
      float4 vb = *(const float4*)&xb[(size_t)(j0+r)*768 + k0 + kq*4];
      As[kq*4+0][r]=va.x; As[kq*4+1][r]=va.y; As[kq*4+2][r]=va.z; As[kq*4+3][r]=va.w;
      Bs[kq*4+0][r]=vb.x; Bs[kq*4+1][r]=vb.y; Bs[kq*4+2][r]=vb.z; Bs[kq*4+3][r]=vb.w;
    }
    __syncthreads();
    for (int kk=0;kk<128;kk++){
      float a0=As[kk][ty*2], a1=As[kk][ty*2+1];
      float b0=Bs[kk][tx*2], b1=Bs[kk][tx*2+1];
      acc[0][0]=fmaf(a0,b0,acc[0][0]); acc[0][1]=fmaf(a0,b1,acc[0][1]);
      acc[1][0]=fmaf(a1,b0,acc[1][0]); acc[1][1]=fmaf(a1,b1,acc[1][1]);
    }
    __syncthreads();
  }
  float invi[2], invj[2];
  invi[0]=inv[b*Eq + i0+ty*2]; invi[1]=inv[b*Eq + i0+ty*2+1];
  invj[0]=inv[b*Eq + j0+tx*2]; invj[1]=inv[b*Eq + j0+tx*2+1];
  float* sb = sim + (size_t)b*Eq*Eq;
  #pragma unroll
  for (int r=0;r<2;r++)
    #pragma unroll
    for (int c=0;c<2;c++)
      sb[(size_t)(i0+ty*2+r)*Eq + j0+tx*2+c] = acc[r][c]*invi[r]*invj[c];
}

// ---------------- top-6 per row: one wave per row (4 rows/block, 1536 blocks) ----------------
__global__ __launch_bounds__(256) void k_topk(const float* __restrict__ sim, unsigned char* __restrict__ A){
  int row = blockIdx.x*4 + (threadIdx.x>>6);
  int lane = threadIdx.x & 63;
  int b = row>>7, i = row&127;
  const float* r = sim + (size_t)b*Eq*Eq + (size_t)i*Eq;
  float x0 = r[lane], x1 = r[64+lane];
  unsigned char a0=0, a1=0;
  #pragma unroll
  for (int k=0;k<6;k++){
    float m; int idx;
    if (x0 >= x1){ m=x0; idx=lane; } else { m=x1; idx=64+lane; }
    #pragma unroll
    for (int off=32; off; off>>=1){
      float om = __shfl_xor(m, off, 64);
      int oi = __shfl_xor(idx, off, 64);
      if (om > m || (om == m && oi < idx)){ m = om; idx = oi; }
    }
    if (m > 0.1f && idx != i){
      if (idx == lane) a0 = 1;
      if (idx == 64+lane) a1 = 1;
    }
    if (idx == lane) x0 = -1e30f;
    if (idx == 64+lane) x1 = -1e30f;
  }
  if (lane == i) a0 = 1;
  if (64+lane == i) a1 = 1;
  unsigned char* Ar = A + (size_t)b*Eq*Eq + (size_t)i*Eq;
  Ar[lane] = a0; Ar[64+lane] = a1;
}

// ---------------- h1 = x @ W_g1 (768->512): 4-wave blocks, no LDS ----------------
// grid (192, 2): wave covers cols blockIdx.y*256 + wave*64 .. +63
__global__ __launch_bounds__(256) void k_h1(const float* __restrict__ x, const unsigned short* __restrict__ Wg1t,
                                            float* __restrict__ h1){
  int tid = threadIdx.x, wave = tid>>6, lane = tid&63, m_ = lane&15, kq = lane>>4;
  size_t row0 = (size_t)blockIdx.x*32;
  int n0 = blockIdx.y*256 + wave*64;
  const float* A0 = x + (row0 + m_)*Hq + kq*8;
  const float* A1 = A0 + 16*Hq;
  const unsigned short* Wb = Wg1t + (size_t)(n0 + m_)*768 + kq*8;
  const f32x4 z = {0.f,0.f,0.f,0.f};
  f32x4 acc[2][4];
  #pragma unroll
  for (int rt=0;rt<2;rt++)
    #pragma unroll
    for (int ct=0;ct<4;ct++) acc[rt][ct]=z;
  for (int k0=0; k0<768; k0+=32){
    float4 l0 = *(const float4*)(A0 + k0);
    float4 h0 = *(const float4*)(A0 + k0 + 4);
    float4 l1 = *(const float4*)(A1 + k0);
    float4 h1v = *(const float4*)(A1 + k0 + 4);
    s16x8 b0 = *(const s16x8*)(Wb + k0);
    s16x8 b1v = *(const s16x8*)(Wb + 16*768 + k0);
    s16x8 b2v = *(const s16x8*)(Wb + 32*768 + k0);
    s16x8 b3v = *(const s16x8*)(Wb + 48*768 + k0);
    s16x8 a0 = pack_bf8(l0,h0);
    s16x8 a1 = pack_bf8(l1,h1v);
    acc[0][0]=MFMA16(a0,b0 ,acc[0][0]); acc[1][0]=MFMA16(a1,b0 ,acc[1][0]);
    acc[0][1]=MFMA16(a0,b1v,acc[0][1]); acc[1][1]=MFMA16(a1,b1v,acc[1][1]);
    acc[0][2]=MFMA16(a0,b2v,acc[0][2]); acc[1][2]=MFMA16(a1,b2v,acc[1][2]);
    acc[0][3]=MFMA16(a0,b3v,acc[0][3]); acc[1][3]=MFMA16(a1,b3v,acc[1][3]);
  }
  #pragma unroll
  for (int ct=0;ct<4;ct++){
    int col = n0 + ct*16 + m_;
    #pragma unroll
    for (int rt=0;rt<2;rt++)
      #pragma unroll
      for (int rg=0;rg<4;rg++){
        int row = rt*16 + kq*4 + rg;
        h1[(row0+row)*512 + col] = acc[rt][ct][rg];
      }
  }
}

// ---------------- s1,d1 attention scores ----------------
__global__ __launch_bounds__(256) void k_sd1(const float* __restrict__ h1, const float* __restrict__ as1,
      const float* __restrict__ ad1, float* __restrict__ s1, float* __restrict__ d1){
  int gw = (blockIdx.x*256 + threadIdx.x)>>6;
  int lane = threadIdx.x & 63;
  if (gw >= Bq*Eq) return;
  const float* hr = h1 + (size_t)gw*512;
  int hd = lane>>4;
  int i0 = lane*8;
  float4 va = *(const float4*)&hr[i0];
  float4 vb = *(const float4*)&hr[i0+4];
  float av[8] = {va.x,va.y,va.z,va.w,vb.x,vb.y,vb.z,vb.w};
  float ps=0.f, pd=0.f;
  #pragma unroll
  for (int u=0;u<8;u++){
    ps += av[u]*as1[i0+u];
    pd += av[u]*ad1[i0+u];
  }
  #pragma unroll
  for (int off=8; off; off>>=1){ ps += __shfl_down(ps,off,16); pd += __shfl_down(pd,off,16); }
  if ((lane&15)==0){ s1[(size_t)gw*4+hd]=ps; d1[(size_t)gw*4+hd]=pd; }
}

// ---------------- GAT1 ----------------
__global__ __launch_bounds__(256) void k_gat1(const float* __restrict__ h1, const float* __restrict__ s1,
      const float* __restrict__ d1, const unsigned char* __restrict__ A,
      const float* __restrict__ bg1, const float* __restrict__ gam, const float* __restrict__ bet,
      float* __restrict__ g1){
  __shared__ float alpha[4][128];
  __shared__ int nbr[128];
  __shared__ int nnz_s;
  __shared__ float outv[512];
  __shared__ float red[8];
  __shared__ float mv_s, rstd_s;
  int bt = blockIdx.x; int b = bt>>7, t = bt&127;
  int tid = threadIdx.x;
  if (tid==0) nnz_s = 0;
  __syncthreads();
  const unsigned char* Ab = A + (size_t)b*Eq*Eq;
  if (tid < 128){
    if (Ab[(size_t)tid*Eq + t]){ int p = atomicAdd(&nnz_s, 1); nbr[p] = tid; }
  }
  __syncthreads();
  int nnz = nnz_s;
  for (int idx=tid; idx<nnz*4; idx+=256){
    int k = idx>>2, hd = idx&3;
    int s = nbr[k];
    float ev = s1[(size_t)(b*Eq+s)*4 + hd] + d1[(size_t)bt*4 + hd];
    alpha[hd][k] = ev>0.f ? ev : 0.2f*ev;
  }
  __syncthreads();
  if (tid < 4){
    float m = -1e30f;
    for (int k=0;k<nnz;k++) m = fmaxf(m, alpha[tid][k]);
    float ss = 0.f;
    for (int k=0;k<nnz;k++){ float e = expf(alpha[tid][k]-m); alpha[tid][k]=e; ss+=e; }
    float rs = 1.f/ss;
    for (int k=0;k<nnz;k++) alpha[tid][k] *= rs;
  }
  __syncthreads();
  for (int c=tid; c<512; c+=256){
    int hd = c>>7;
    float o = 0.f;
    for (int k=0;k<nnz;k++) o += alpha[hd][k] * h1[((size_t)b*Eq + nbr[k])*512 + c];
    outv[c] = o + bg1[c];
  }
  __syncthreads();
  float ls=0.f, lq=0.f;
  for (int c=tid;c<512;c+=256){ float v=outv[c]; ls+=v; lq+=v*v; }
  #pragma unroll
  for (int off=32; off; off>>=1){ ls += __shfl_down(ls,off,64); lq += __shfl_down(lq,off,64); }
  int wv_ = tid>>6;
  if ((tid&63)==0){ red[wv_]=ls; red[4+wv_]=lq; }
  __syncthreads();
  if (tid==0){
    float sm=red[0]+red[1]+red[2]+red[3], sq=red[4]+red[5]+red[6]+red[7];
    float m = sm/512.f; mv_s = m; rstd_s = rsqrtf(sq/512.f - m*m + 1e-5f);
  }
  __syncthreads();
  for (int c=tid;c<512;c+=256){
    float v = (outv[c]-mv_s)*rstd_s*gam[c] + bet[c];
    g1[(size_t)bt*512 + c] = v>0.f ? v : expm1f(v);
  }
}

// ---------------- h2 = g1 @ W_g2 (512->64) + s2,d2 ----------------
__global__ __launch_bounds__(256) void k_h2(const float* __restrict__ g1, const float* __restrict__ Wg2,
      const float* __restrict__ as2, const float* __restrict__ ad2,
      float* __restrict__ h2, float* __restrict__ s2, float* __restrict__ d2){
  __shared__ float gt[16*512];
  int tid=threadIdx.x;
  size_t row0 = (size_t)blockIdx.x*16;
  const float4* src = (const float4*)(g1 + row0*512);
  for (int v=tid; v<2048; v+=256) *(float4*)&gt[v*4] = src[v];
  __syncthreads();
  int w = tid>>6, lane = tid&63;
  float acc[4];
  #pragma unroll
  for (int r=0;r<4;r++) acc[r]=0.f;
  for (int k=0;k<512;k+=4){
    float w0=Wg2[(k+0)*64+lane];
    float w1=Wg2[(k+1)*64+lane];
    float w2=Wg2[(k+2)*64+lane];
    float w3=Wg2[(k+3)*64+lane];
    #pragma unroll
    for (int r=0;r<4;r++){
      const float4 t = *(const float4*)&gt[(w*4+r)*512 + k];
      acc[r]=fmaf(t.x,w0,acc[r]);
      acc[r]=fmaf(t.y,w1,acc[r]);
      acc[r]=fmaf(t.z,w2,acc[r]);
      acc[r]=fmaf(t.w,w3,acc[r]);
    }
  }
  float as_=as2[lane], ad_=ad2[lane];
  #pragma unroll
  for (int r=0;r<4;r++){
    size_t row = row0 + w*4 + r;
    h2[row*64 + lane] = acc[r];
    float ps = acc[r]*as_, pd = acc[r]*ad_;
    #pragma unroll
    for (int off=32; off; off>>=1){ ps += __shfl_down(ps,off,64); pd += __shfl_down(pd,off,64); }
    if (lane==0){ s2[row]=ps; d2[row]=pd; }
  }
}

// ---------------- GAT2 ----------------
__global__ __launch_bounds__(64) void k_gat2(const float* __restrict__ h2, const float* __restrict__ s2,
      const float* __restrict__ d2, const unsigned char* __restrict__ A,
      const float* __restrict__ bg2, const float* __restrict__ gam, const float* __restrict__ bet,
      float* __restrict__ ent){
  __shared__ float alpha[128];
  __shared__ int nbr[128];
  __shared__ int nnz_s;
  int bt = blockIdx.x; int b = bt>>7, t = bt&127;
  int tid=threadIdx.x;
  if (tid==0) nnz_s=0;
  __syncthreads();
  const unsigned char* Ab = A + (size_t)b*Eq*Eq;
  for (int s=tid; s<128; s+=64) if (Ab[(size_t)s*Eq + t]) { int p=atomicAdd(&nnz_s,1); nbr[p]=s; }
  __syncthreads();
  int nnz = nnz_s;
  float dt = d2[bt];
  for (int k=tid; k<nnz; k+=64){
    float ev = s2[(size_t)b*Eq + nbr[k]] + dt;
    alpha[k] = ev>0.f ? ev : 0.2f*ev;
  }
  __syncthreads();
  if (tid==0){
    float m=-1e30f;
    for (int k=0;k<nnz;k++) m = fmaxf(m, alpha[k]);
    float ss=0.f;
    for (int k=0;k<nnz;k++){ float e=expf(alpha[k]-m); alpha[k]=e; ss+=e; }
    float rs=1.f/ss;
    for (int k=0;k<nnz;k++) alpha[k]*=rs;
  }
  __syncthreads();
  float o = bg2[tid];
  for (int k=0;k<nnz;k++) o += alpha[k]*h2[((size_t)b*Eq + nbr[k])*64 + tid];
  float sv = o, qv = o*o;
  #pragma unroll
  for (int off=1; off<64; off<<=1){ sv += __shfl_xor(sv,off,64); qv += __shfl_xor(qv,off,64); }
  float m = sv*(1.f/64.f);
  float var = qv*(1.f/64.f) - m*m;
  float v = (o-m)*rsqrtf(var+1e-5f)*gam[tid] + bet[tid];
  ent[(size_t)bt*64 + tid] = v>0.f ? v : expm1f(v);
}

// ---------------- relation head: 16-row tiles (LDS 30KB, grid 768) ----------------
__global__ __launch_bounds__(256) void k_rel(const float* __restrict__ ent, const float* __restrict__ seq,
      const float* __restrict__ rel_emb, const int* __restrict__ ph, const int* __restrict__ pt,
      const int* __restrict__ pr, const unsigned short* __restrict__ Wr1t, const float* __restrict__ br1,
      const float* __restrict__ Wr2, const float* __restrict__ br2, float* __restrict__ out){
  __shared__ unsigned short As[16*936];   // 29,952 B
  unsigned short* Hs = As;                // hidden 16x264 aliased after K-loop
  int tid = threadIdx.x;
  int p0 = blockIdx.x*16;
  for (int idx=tid; idx<16*928; idx+=256){
    int r = idx/928, c = idx - r*928;
    int gp = p0 + r; int b = gp>>8, pp = gp&255;
    float v;
    if (c < 64)      v = ent[((size_t)b*Eq + ph[b*Pq+pp])*64 + c];
    else if (c<128)  v = ent[((size_t)b*Eq + pt[b*Pq+pp])*64 + (c-64)];
    else if (c<160)  v = rel_emb[pr[b*Pq+pp]*32 + (c-128)];
    else             v = seq[(size_t)b*Sq*Hq + (c-160)];
    As[r*936 + c] = f2bf(v);
  }
  __syncthreads();
  int wave = tid>>6, lane = tid&63, m_ = lane&15, kq = lane>>4;
  int n0 = wave*64;
  const f32x4 z = {0.f,0.f,0.f,0.f};
  f32x4 acc[4];
  #pragma unroll
  for (int ct=0;ct<4;ct++) acc[ct]=z;
  const unsigned short* Wb = Wr1t + (size_t)(n0 + m_)*928 + kq*8;
  for (int k0=0; k0<928; k0+=32){
    s16x8 a0 = *(const s16x8*)&As[m_*936 + k0 + kq*8];
    s16x8 b0 = *(const s16x8*)(Wb + k0);
    s16x8 b1v = *(const s16x8*)(Wb + 16*928 + k0);
    s16x8 b2v = *(const s16x8*)(Wb + 32*928 + k0);
    s16x8 b3v = *(const s16x8*)(Wb + 48*928 + k0);
    acc[0]=MFMA16(a0,b0 ,acc[0]);
    acc[1]=MFMA16(a0,b1v,acc[1]);
    acc[2]=MFMA16(a0,b2v,acc[2]);
    acc[3]=MFMA16(a0,b3v,acc[3]);
  }
  __syncthreads();
  #pragma unroll
  for (int ct=0;ct<4;ct++){
    int col = n0 + ct*16 + m_;
    float bb = br1[col];
    #pragma unroll
    for (int rg=0;rg<4;rg++){
      int row = kq*4 + rg;
      Hs[row*264 + col] = f2bf(fmaxf(acc[ct][rg] + bb, 0.f));
    }
  }
  __syncthreads();
  {
    int r2 = tid>>4, q = tid&15;   // 16 rows x 16 threads
    float p = 0.f;
    for (int u=q*16; u<q*16+16; u++) p += bfu2f(Hs[r2*264+u]) * Wr2[u];
    #pragma unroll
    for (int off=8; off; off>>=1) p += __shfl_down(p, off, 16);
    if (q==0) out[NER_TOT + p0 + r2] = p + br2[0];
  }
}

extern "C" void kernel_launch(void* const* d_in, const int* in_sizes, int n_in,
                              void* d_out, int out_size, void* d_ws, size_t ws_size,
                              hipStream_t stream){
  const float* seq      = (const float*)d_in[0];
  const int*  sstart   = (const int*)d_in[1];
  const int*  slen     = (const int*)d_in[2];
  const int*  etype    = (const int*)d_in[3];
  const int*  ph       = (const int*)d_in[4];
  const int*  pt       = (const int*)d_in[5];
  const int*  pr       = (const int*)d_in[6];
  const float* W_ner1   = (const float*)d_in[7];
  const float* b_ner1   = (const float*)d_in[8];
  const float* W_ner2   = (const float*)d_in[9];
  const float* b_ner2   = (const float*)d_in[10];
  const float* type_emb = (const float*)d_in[11];
  const float* W_g1     = (const float*)d_in[12];
  const float* a_src1   = (const float*)d_in[13];
  const float* a_dst1   = (const float*)d_in[14];
  const float* b_g1     = (const float*)d_in[15];
  const float* g1_gamma = (const float*)d_in[16];
  const float* g1_beta  = (const float*)d_in[17];
  const float* W_g2     = (const float*)d_in[18];
  const float* a_src2   = (const float*)d_in[19];
  const float* a_dst2   = (const float*)d_in[20];
  const float* b_g2     = (const float*)d_in[21];
  const float* g2_gamma = (const float*)d_in[22];
  const float* g2_beta  = (const float*)d_in[23];
  const float* rel_emb  = (const float*)d_in[24];
  const float* W_r1     = (const float*)d_in[25];
  const float* b_r1     = (const float*)d_in[26];
  const float* W_r2     = (const float*)d_in[27];
  const float* b_r2     = (const float*)d_in[28];
  float* outp = (float*)d_out;

  float* x    = (float*)d_ws;                       // 4,718,592 f
  float* g1   = x;                                  // alias: x dead after k_h1
  float* inv  = x   + (size_t)Bq*Eq*Hq;             // 6,144 f
  float* sim  = inv + Bq*Eq;                        // 786,432 f
  float* h2   = sim;                                // alias: sim dead after k_topk
  float* s2   = h2  + (size_t)Bq*Eq*64;             // 6,144 f
  float* d2   = s2  + Bq*Eq;                        // 6,144 f
  float* h1   = sim + (size_t)Bq*Eq*Eq;             // 3,145,728 f
  float* s1   = h1  + (size_t)Bq*Eq*512;            // 24,576 f
  float* d1   = s1  + Bq*Eq*4;                      // 24,576 f
  float* entp = d1  + Bq*Eq*4;                      // 393,216 f
  unsigned char* A = (unsigned char*)(entp + (size_t)Bq*Eq*64);  // 786,432 B
  unsigned short* W1t  = (unsigned short*)(A + (size_t)Bq*Eq*Eq); // 196,608 ush
  unsigned short* W2t  = W1t  + 196608;                           // 4,096 ush
  unsigned short* Wg1t = W2t  + 4096;                             // 393,216 ush
  unsigned short* Wr1t = Wg1t + 393216;                           // 237,568 ush
  // hid (24576x256 bf16) aliases sim+h1 region; dead before k_sim/k_h1 write it.
  unsigned short* hid  = (unsigned short*)sim;

  k_prep<<<3248, 256, 0, stream>>>(W_ner1, W_ner2, W_g1, W_r1, W1t, W2t, Wg1t, Wr1t);
  k_ner1<<<768, 256, 0, stream>>>(seq, W1t, b_ner1, hid);
  k_ner2<<<384, 256, 0, stream>>>(hid, W2t, b_ner2, outp);
  k_span<<<Bq*Eq, 256, 0, stream>>>(seq, sstart, slen, etype, type_emb, x, inv);
  k_sim <<<dim3(4,4,Bq), 256, 0, stream>>>(x, inv, sim);
  k_topk<<<1536, 256, 0, stream>>>(sim, A);
  k_h1  <<<dim3(192,2), 256, 0, stream>>>(x, Wg1t, h1);          // x dead after this
  k_sd1 <<<1536, 256, 0, stream>>>(h1, a_src1, a_dst1, s1, d1);
  k_gat1<<<Bq*Eq, 256, 0, stream>>>(h1, s1, d1, A, b_g1, g1_gamma, g1_beta, g1);
  k_h2  <<<384, 256, 0, stream>>>(g1, W_g2, a_src2, a_dst2, h2, s2, d2);  // sim dead
  k_gat2<<<Bq*Eq, 64, 0, stream>>>(h2, s2, d2, A, b_g2, g2_gamma, g2_beta, entp);
  k_rel <<<768, 256, 0, stream>>>(entp, seq, rel_emb, ph, pt, pr, Wr1t, b_r1, W_r2, b_r2, outp);
}

// Round 11
// 382.108 us; speedup vs baseline: 1.2455x; 1.2455x over previous
//
#include <hip/hip_runtime.h>
#include <hip/hip_bf16.h>
#include <math.h>

#define Bq 48
#define Sq 512
#define Hq 768
#define Eq 128
#define Lq 16
#define Pq 256
#define NERq 11
#define NER_TOT (Bq*Sq*NERq)   // 270336

typedef __attribute__((ext_vector_type(8))) short s16x8;   // 8 bf16 = 4 VGPR
typedef __attribute__((ext_vector_type(4))) float f32x4;
#define MFMA16(a,b,c) __builtin_amdgcn_mfma_f32_16x16x32_bf16(a,b,c,0,0,0)

// f32 -> bf16 bits, round-to-nearest-even
__device__ __forceinline__ unsigned short f2bf(float f){
  union{float f; unsigned u;} v; v.f=f;
  unsigned r = v.u + 0x7fffu + ((v.u>>16)&1u);
  return (unsigned short)(r>>16);
}
__device__ __forceinline__ float bfu2f(unsigned short h){
  union{unsigned u; float f;} c; c.u = ((unsigned)h)<<16; return c.f;
}

// ---------------- prep: weights -> bf16 in MFMA-fragment-contiguous order ----------------
// Layout: Ws[kb][nt][lane][j]  (kb = k0/32, nt = 16-col group, 64 lanes, 8 halves)
// element = W[k = kb*32 + (lane>>4)*8 + j][n = nt*16 + (lane&15)]
// -> a wave's B-fragment load for (kb,nt) is base + lane*16B: fully coalesced.
__global__ __launch_bounds__(256) void k_prep(const float* __restrict__ W1, const float* __restrict__ W2,
      const float* __restrict__ Wg1, const float* __restrict__ Wr1,
      unsigned short* __restrict__ W1s, unsigned short* __restrict__ W2t,
      unsigned short* __restrict__ Wg1s, unsigned short* __restrict__ Wr1s){
  int i = blockIdx.x*256 + threadIdx.x;   // 831488 total = 3248*256
  if (i < 196608){            // W1s: N=256 (NT=16), K=768 (24 kb)
    int j = i&7, lane = (i>>3)&63, rem = i>>9;
    int nt = rem&15, kb = rem>>4;
    int k = kb*32 + (lane>>4)*8 + j, n = nt*16 + (lane&15);
    W1s[i] = f2bf(W1[k*256 + n]);
  } else if (i < 200704){     // W2t: 16x256, rows 11..15 zero (unchanged layout)
    int j = i - 196608; int n = j>>8, k = j&255;
    W2t[j] = (n < NERq) ? f2bf(W2[k*NERq + n]) : 0;
  } else if (i < 593920){     // Wg1s: N=512 (NT=32), K=768 (24 kb)
    int q = i - 200704;
    int j = q&7, lane = (q>>3)&63, rem = q>>9;
    int nt = rem&31, kb = rem>>5;
    int k = kb*32 + (lane>>4)*8 + j, n = nt*16 + (lane&15);
    Wg1s[q] = f2bf(Wg1[k*512 + n]);
  } else {                    // Wr1s: N=256 (NT=16), K=928 (29 kb)
    int q = i - 593920;
    int j = q&7, lane = (q>>3)&63, rem = q>>9;
    int nt = rem&15, kb = rem>>4;
    int k = kb*32 + (lane>>4)*8 + j, n = nt*16 + (lane&15);
    Wr1s[q] = f2bf(Wr1[k*256 + n]);
  }
}

// ---------------- NER layer 1: 8-wave blocks, LDS A-tile, coalesced swizzled B ----------------
// grid 768: block = rows bx*32..+31 x all 256 cols; wave w covers cols w*32..+31 (nt = 2w,2w+1)
__global__ __launch_bounds__(512) void k_ner1(const float* __restrict__ seq, const unsigned short* __restrict__ W1s,
      const float* __restrict__ b1, unsigned short* __restrict__ hid){
  __shared__ unsigned short As[32*776];   // 48.4KB -> 3 blocks/CU, 24 waves/CU
  int tid = threadIdx.x;
  size_t row0 = (size_t)blockIdx.x*32;
  const float4* src = (const float4*)(seq + row0*Hq);
  for (int v=tid; v<6144; v+=512){
    float4 f = src[v];
    int r = v/192, k = (v - r*192)*4;
    ushort4 h = { f2bf(f.x), f2bf(f.y), f2bf(f.z), f2bf(f.w) };
    *(ushort4*)&As[r*776 + k] = h;
  }
  __syncthreads();
  int wave = tid>>6, lane = tid&63, m_ = lane&15, kq = lane>>4;
  const f32x4 z = {0.f,0.f,0.f,0.f};
  f32x4 acc[2][2];
  acc[0][0]=z; acc[0][1]=z; acc[1][0]=z; acc[1][1]=z;
  const unsigned short* Wb = W1s + (size_t)lane*8;
  for (int kb=0; kb<24; kb++){
    int k0 = kb*32;
    s16x8 a0 = *(const s16x8*)&As[m_*776 + k0 + kq*8];
    s16x8 a1 = *(const s16x8*)&As[(16+m_)*776 + k0 + kq*8];
    s16x8 b0 = *(const s16x8*)(Wb + ((size_t)kb*16 + 2*wave  )*512);
    s16x8 b1 = *(const s16x8*)(Wb + ((size_t)kb*16 + 2*wave+1)*512);
    acc[0][0]=MFMA16(a0,b0,acc[0][0]); acc[1][0]=MFMA16(a1,b0,acc[1][0]);
    acc[0][1]=MFMA16(a0,b1,acc[0][1]); acc[1][1]=MFMA16(a1,b1,acc[1][1]);
  }
  #pragma unroll
  for (int ct=0;ct<2;ct++){
    int col = wave*32 + ct*16 + m_;
    float bb = b1[col];
    #pragma unroll
    for (int rt=0;rt<2;rt++)
      #pragma unroll
      for (int rg=0;rg<4;rg++){
        int row = rt*16 + kq*4 + rg;
        hid[(row0+row)*256 + col] = f2bf(fmaxf(acc[rt][ct][rg] + bb, 0.f));
      }
  }
}

// ---------------- NER layer 2: hidden(bf16) @ W2t, K=256; 4-wave blocks ----------------
__global__ __launch_bounds__(256) void k_ner2(const unsigned short* __restrict__ hid,
      const unsigned short* __restrict__ W2t, const float* __restrict__ b2, float* __restrict__ out){
  int tid = threadIdx.x, wave = tid>>6, lane = tid&63, m_ = lane&15, kq = lane>>4;
  size_t row0 = (size_t)blockIdx.x*64 + wave*16;   // 384 blocks
  f32x4 a2 = {0.f,0.f,0.f,0.f};
  for (int k0=0;k0<256;k0+=32){
    s16x8 a = *(const s16x8*)&hid[(row0+m_)*256 + k0 + kq*8];
    s16x8 b = *(const s16x8*)&W2t[m_*256 + k0 + kq*8];
    a2 = MFMA16(a,b,a2);
  }
  if (m_ < NERq){
    float bb = b2[m_];
    #pragma unroll
    for (int rg=0;rg<4;rg++)
      out[(row0+kq*4+rg)*NERq + m_] = a2[rg] + bb;
  }
}

// ---------------- span pooling: register-staged tokens ----------------
__global__ __launch_bounds__(256) void k_span(const float* __restrict__ seq, const int* __restrict__ sstart,
      const int* __restrict__ slen, const int* __restrict__ etype, const float* __restrict__ type_emb,
      float* __restrict__ x, float* __restrict__ inv){
  __shared__ float red16[4][16];
  __shared__ float wv[16];
  __shared__ float redn[4];
  int be = blockIdx.x;
  int b = be >> 7;
  int tid = threadIdx.x;
  int wave = tid>>6, lane = tid&63;
  int st = sstart[be], ln = slen[be];
  int cnt = ln + 1;                // mask = pos <= len; rows >= cnt have weight exactly 0
  const float* base = seq + ((size_t)b*Sq + st)*Hq;
  float tokr[16][3];
  #pragma unroll
  for (int l=0;l<16;l++){
    if (l < cnt){
      tokr[l][0] = base[l*768 + tid];
      tokr[l][1] = base[l*768 + tid + 256];
      tokr[l][2] = base[l*768 + tid + 512];
    } else {
      tokr[l][0]=0.f; tokr[l][1]=0.f; tokr[l][2]=0.f;
    }
  }
  float meanr[3];
  #pragma unroll
  for (int c=0;c<3;c++){
    float s=0.f;
    #pragma unroll
    for (int l=0;l<16;l++) if (l < cnt) s += tokr[l][c];
    meanr[c] = s/(float)cnt;
  }
  #pragma unroll
  for (int l=0;l<16;l++){
    if (l < cnt){
      float p = tokr[l][0]*meanr[0] + tokr[l][1]*meanr[1] + tokr[l][2]*meanr[2];
      #pragma unroll
      for (int off=32; off; off>>=1) p += __shfl_down(p, off, 64);
      if (lane==0) red16[wave][l] = p;
    }
  }
  __syncthreads();
  if (tid==0){
    float sc[16];
    for (int l=0;l<cnt;l++) sc[l] = red16[0][l]+red16[1][l]+red16[2][l]+red16[3][l];
    float m=-1e30f;
    for (int l=0;l<cnt;l++) m = fmaxf(m, sc[l]);
    float ssum=0.f;
    float e[16];
    for (int l=0;l<16;l++){
      e[l] = (l<cnt) ? expf(sc[l]-m) : 0.f;
      ssum += e[l];
    }
    float rs = 1.f/ssum;
    for (int l=0;l<16;l++) wv[l] = e[l]*rs;
  }
  __syncthreads();
  const float* te = type_emb + (size_t)etype[be]*Hq;
  float nrm = 0.f;
  #pragma unroll
  for (int c=0;c<3;c++){
    int h = tid + c*256;
    float p=0.f;
    #pragma unroll
    for (int l=0;l<16;l++) if (l < cnt) p += wv[l]*tokr[l][c];
    float xv = p + te[h];
    x[(size_t)be*Hq + h] = xv;
    nrm += xv*xv;
  }
  #pragma unroll
  for (int off=32; off; off>>=1) nrm += __shfl_down(nrm, off, 64);
  if (lane==0) redn[wave]=nrm;
  __syncthreads();
  if (tid==0){
    float t = redn[0]+redn[1]+redn[2]+redn[3];
    inv[be] = 1.f/fmaxf(sqrtf(t), 1e-12f);
  }
}

// ---------------- sim: 32x32 tiles, K-chunks of 128, 768 blocks ----------------
__global__ __launch_bounds__(256) void k_sim(const float* __restrict__ x, const float* __restrict__ inv,
                                             float* __restrict__ sim){
  __shared__ float As[128][33];
  __shared__ float Bs[128][33];
  int b = blockIdx.z;
  int i0 = blockIdx.y*32, j0 = blockIdx.x*32;
  int tid = threadIdx.x;
  int ty = tid>>4, tx = tid&15;
  float acc[2][2] = {{0.f,0.f},{0.f,0.f}};
  const float* xb = x + (size_t)b*Eq*Hq;
  for (int k0=0;k0<768;k0+=128){
    for (int idx=tid; idx<1024; idx+=256){
      int kq = idx&31, r = idx>>5;
      float4 va = *(const float4*)&xb[(size_t)(i0+r)*768 + k0 + kq*4];
      float4 vb = *(const float4*)&xb[(size_t)(j0+r)*768 + k0 + kq*4];
      As[kq*4+0][r]=va.x; As[kq*4+1][r]=va.y; As[kq*4+2][r]=va.z; As[kq*4+3][r]=va.w;
      Bs[kq*4+0][r]=vb.x; Bs[kq*4+1][r]=vb.y; Bs[kq*4+2][r]=vb.z; Bs[kq*4+3][r]=vb.w;
    }
    __syncthreads();
    for (int kk=0;kk<128;kk++){
      float a0=As[kk][ty*2], a1=As[kk][ty*2+1];
      float b0=Bs[kk][tx*2], b1=Bs[kk][tx*2+1];
      acc[0][0]=fmaf(a0,b0,acc[0][0]); acc[0][1]=fmaf(a0,b1,acc[0][1]);
      acc[1][0]=fmaf(a1,b0,acc[1][0]); acc[1][1]=fmaf(a1,b1,acc[1][1]);
    }
    __syncthreads();
  }
  float invi[2], invj[2];
  invi[0]=inv[b*Eq + i0+ty*2]; invi[1]=inv[b*Eq + i0+ty*2+1];
  invj[0]=inv[b*Eq + j0+tx*2]; invj[1]=inv[b*Eq + j0+tx*2+1];
  float* sb = sim + (size_t)b*Eq*Eq;
  #pragma unroll
  for (int r=0;r<2;r++)
    #pragma unroll
    for (int c=0;c<2;c++)
      sb[(size_t)(i0+ty*2+r)*Eq + j0+tx*2+c] = acc[r][c]*invi[r]*invj[c];
}

// ---------------- top-6 per row: one wave per row (4 rows/block, 1536 blocks) ----------------
__global__ __launch_bounds__(256) void k_topk(const float* __restrict__ sim, unsigned char* __restrict__ A){
  int row = blockIdx.x*4 + (threadIdx.x>>6);
  int lane = threadIdx.x & 63;
  int b = row>>7, i = row&127;
  const float* r = sim + (size_t)b*Eq*Eq + (size_t)i*Eq;
  float x0 = r[lane], x1 = r[64+lane];
  unsigned char a0=0, a1=0;
  #pragma unroll
  for (int k=0;k<6;k++){
    float m; int idx;
    if (x0 >= x1){ m=x0; idx=lane; } else { m=x1; idx=64+lane; }
    #pragma unroll
    for (int off=32; off; off>>=1){
      float om = __shfl_xor(m, off, 64);
      int oi = __shfl_xor(idx, off, 64);
      if (om > m || (om == m && oi < idx)){ m = om; idx = oi; }
    }
    if (m > 0.1f && idx != i){
      if (idx == lane) a0 = 1;
      if (idx == 64+lane) a1 = 1;
    }
    if (idx == lane) x0 = -1e30f;
    if (idx == 64+lane) x1 = -1e30f;
  }
  if (lane == i) a0 = 1;
  if (64+lane == i) a1 = 1;
  unsigned char* Ar = A + (size_t)b*Eq*Eq + (size_t)i*Eq;
  Ar[lane] = a0; Ar[64+lane] = a1;
}

// ---------------- h1 = x @ W_g1 (768->512): 8-wave blocks, LDS A-tile, swizzled B ----------------
// grid (192, 2): block = rows bx*32..+31, cols by*256 + wave*32..+31
__global__ __launch_bounds__(512) void k_h1(const float* __restrict__ x, const unsigned short* __restrict__ Wg1s,
                                            float* __restrict__ h1){
  __shared__ unsigned short As[32*776];
  int tid = threadIdx.x;
  size_t row0 = (size_t)blockIdx.x*32;
  const float4* src = (const float4*)(x + row0*Hq);
  for (int v=tid; v<6144; v+=512){
    float4 f = src[v];
    int r = v/192, k = (v - r*192)*4;
    ushort4 h = { f2bf(f.x), f2bf(f.y), f2bf(f.z), f2bf(f.w) };
    *(ushort4*)&As[r*776 + k] = h;
  }
  __syncthreads();
  int wave = tid>>6, lane = tid&63, m_ = lane&15, kq = lane>>4;
  int ntb = blockIdx.y*16 + 2*wave;      // nt group base (NT=32 total)
  const f32x4 z = {0.f,0.f,0.f,0.f};
  f32x4 acc[2][2];
  acc[0][0]=z; acc[0][1]=z; acc[1][0]=z; acc[1][1]=z;
  const unsigned short* Wb = Wg1s + (size_t)lane*8;
  for (int kb=0; kb<24; kb++){
    int k0 = kb*32;
    s16x8 a0 = *(const s16x8*)&As[m_*776 + k0 + kq*8];
    s16x8 a1 = *(const s16x8*)&As[(16+m_)*776 + k0 + kq*8];
    s16x8 b0 = *(const s16x8*)(Wb + ((size_t)kb*32 + ntb  )*512);
    s16x8 b1 = *(const s16x8*)(Wb + ((size_t)kb*32 + ntb+1)*512);
    acc[0][0]=MFMA16(a0,b0,acc[0][0]); acc[1][0]=MFMA16(a1,b0,acc[1][0]);
    acc[0][1]=MFMA16(a0,b1,acc[0][1]); acc[1][1]=MFMA16(a1,b1,acc[1][1]);
  }
  #pragma unroll
  for (int ct=0;ct<2;ct++){
    int col = (ntb+ct)*16 + m_;
    #pragma unroll
    for (int rt=0;rt<2;rt++)
      #pragma unroll
      for (int rg=0;rg<4;rg++){
        int row = rt*16 + kq*4 + rg;
        h1[(row0+row)*512 + col] = acc[rt][ct][rg];
      }
  }
}

// ---------------- s1,d1 attention scores ----------------
__global__ __launch_bounds__(256) void k_sd1(const float* __restrict__ h1, const float* __restrict__ as1,
      const float* __restrict__ ad1, float* __restrict__ s1, float* __restrict__ d1){
  int gw = (blockIdx.x*256 + threadIdx.x)>>6;
  int lane = threadIdx.x & 63;
  if (gw >= Bq*Eq) return;
  const float* hr = h1 + (size_t)gw*512;
  int hd = lane>>4;
  int i0 = lane*8;
  float4 va = *(const float4*)&hr[i0];
  float4 vb = *(const float4*)&hr[i0+4];
  float av[8] = {va.x,va.y,va.z,va.w,vb.x,vb.y,vb.z,vb.w};
  float ps=0.f, pd=0.f;
  #pragma unroll
  for (int u=0;u<8;u++){
    ps += av[u]*as1[i0+u];
    pd += av[u]*ad1[i0+u];
  }
  #pragma unroll
  for (int off=8; off; off>>=1){ ps += __shfl_down(ps,off,16); pd += __shfl_down(pd,off,16); }
  if ((lane&15)==0){ s1[(size_t)gw*4+hd]=ps; d1[(size_t)gw*4+hd]=pd; }
}

// ---------------- GAT1 ----------------
__global__ __launch_bounds__(256) void k_gat1(const float* __restrict__ h1, const float* __restrict__ s1,
      const float* __restrict__ d1, const unsigned char* __restrict__ A,
      const float* __restrict__ bg1, const float* __restrict__ gam, const float* __restrict__ bet,
      float* __restrict__ g1){
  __shared__ float alpha[4][128];
  __shared__ int nbr[128];
  __shared__ int nnz_s;
  __shared__ float outv[512];
  __shared__ float red[8];
  __shared__ float mv_s, rstd_s;
  int bt = blockIdx.x; int b = bt>>7, t = bt&127;
  int tid = threadIdx.x;
  if (tid==0) nnz_s = 0;
  __syncthreads();
  const unsigned char* Ab = A + (size_t)b*Eq*Eq;
  if (tid < 128){
    if (Ab[(size_t)tid*Eq + t]){ int p = atomicAdd(&nnz_s, 1); nbr[p] = tid; }
  }
  __syncthreads();
  int nnz = nnz_s;
  for (int idx=tid; idx<nnz*4; idx+=256){
    int k = idx>>2, hd = idx&3;
    int s = nbr[k];
    float ev = s1[(size_t)(b*Eq+s)*4 + hd] + d1[(size_t)bt*4 + hd];
    alpha[hd][k] = ev>0.f ? ev : 0.2f*ev;
  }
  __syncthreads();
  if (tid < 4){
    float m = -1e30f;
    for (int k=0;k<nnz;k++) m = fmaxf(m, alpha[tid][k]);
    float ss = 0.f;
    for (int k=0;k<nnz;k++){ float e = expf(alpha[tid][k]-m); alpha[tid][k]=e; ss+=e; }
    float rs = 1.f/ss;
    for (int k=0;k<nnz;k++) alpha[tid][k] *= rs;
  }
  __syncthreads();
  for (int c=tid; c<512; c+=256){
    int hd = c>>7;
    float o = 0.f;
    for (int k=0;k<nnz;k++) o += alpha[hd][k] * h1[((size_t)b*Eq + nbr[k])*512 + c];
    outv[c] = o + bg1[c];
  }
  __syncthreads();
  float ls=0.f, lq=0.f;
  for (int c=tid;c<512;c+=256){ float v=outv[c]; ls+=v; lq+=v*v; }
  #pragma unroll
  for (int off=32; off; off>>=1){ ls += __shfl_down(ls,off,64); lq += __shfl_down(lq,off,64); }
  int wv_ = tid>>6;
  if ((tid&63)==0){ red[wv_]=ls; red[4+wv_]=lq; }
  __syncthreads();
  if (tid==0){
    float sm=red[0]+red[1]+red[2]+red[3], sq=red[4]+red[5]+red[6]+red[7];
    float m = sm/512.f; mv_s = m; rstd_s = rsqrtf(sq/512.f - m*m + 1e-5f);
  }
  __syncthreads();
  for (int c=tid;c<512;c+=256){
    float v = (outv[c]-mv_s)*rstd_s*gam[c] + bet[c];
    g1[(size_t)bt*512 + c] = v>0.f ? v : expm1f(v);
  }
}

// ---------------- h2 = g1 @ W_g2 (512->64) + s2,d2 ----------------
__global__ __launch_bounds__(256) void k_h2(const float* __restrict__ g1, const float* __restrict__ Wg2,
      const float* __restrict__ as2, const float* __restrict__ ad2,
      float* __restrict__ h2, float* __restrict__ s2, float* __restrict__ d2){
  __shared__ float gt[16*512];
  int tid=threadIdx.x;
  size_t row0 = (size_t)blockIdx.x*16;
  const float4* src = (const float4*)(g1 + row0*512);
  for (int v=tid; v<2048; v+=256) *(float4*)&gt[v*4] = src[v];
  __syncthreads();
  int w = tid>>6, lane = tid&63;
  float acc[4];
  #pragma unroll
  for (int r=0;r<4;r++) acc[r]=0.f;
  for (int k=0;k<512;k+=4){
    float w0=Wg2[(k+0)*64+lane];
    float w1=Wg2[(k+1)*64+lane];
    float w2=Wg2[(k+2)*64+lane];
    float w3=Wg2[(k+3)*64+lane];
    #pragma unroll
    for (int r=0;r<4;r++){
      const float4 t = *(const float4*)&gt[(w*4+r)*512 + k];
      acc[r]=fmaf(t.x,w0,acc[r]);
      acc[r]=fmaf(t.y,w1,acc[r]);
      acc[r]=fmaf(t.z,w2,acc[r]);
      acc[r]=fmaf(t.w,w3,acc[r]);
    }
  }
  float as_=as2[lane], ad_=ad2[lane];
  #pragma unroll
  for (int r=0;r<4;r++){
    size_t row = row0 + w*4 + r;
    h2[row*64 + lane] = acc[r];
    float ps = acc[r]*as_, pd = acc[r]*ad_;
    #pragma unroll
    for (int off=32; off; off>>=1){ ps += __shfl_down(ps,off,64); pd += __shfl_down(pd,off,64); }
    if (lane==0){ s2[row]=ps; d2[row]=pd; }
  }
}

// ---------------- GAT2 ----------------
__global__ __launch_bounds__(64) void k_gat2(const float* __restrict__ h2, const float* __restrict__ s2,
      const float* __restrict__ d2, const unsigned char* __restrict__ A,
      const float* __restrict__ bg2, const float* __restrict__ gam, const float* __restrict__ bet,
      float* __restrict__ ent){
  __shared__ float alpha[128];
  __shared__ int nbr[128];
  __shared__ int nnz_s;
  int bt = blockIdx.x; int b = bt>>7, t = bt&127;
  int tid=threadIdx.x;
  if (tid==0) nnz_s=0;
  __syncthreads();
  const unsigned char* Ab = A + (size_t)b*Eq*Eq;
  for (int s=tid; s<128; s+=64) if (Ab[(size_t)s*Eq + t]) { int p=atomicAdd(&nnz_s,1); nbr[p]=s; }
  __syncthreads();
  int nnz = nnz_s;
  float dt = d2[bt];
  for (int k=tid; k<nnz; k+=64){
    float ev = s2[(size_t)b*Eq + nbr[k]] + dt;
    alpha[k] = ev>0.f ? ev : 0.2f*ev;
  }
  __syncthreads();
  if (tid==0){
    float m=-1e30f;
    for (int k=0;k<nnz;k++) m = fmaxf(m, alpha[k]);
    float ss=0.f;
    for (int k=0;k<nnz;k++){ float e=expf(alpha[k]-m); alpha[k]=e; ss+=e; }
    float rs=1.f/ss;
    for (int k=0;k<nnz;k++) alpha[k]*=rs;
  }
  __syncthreads();
  float o = bg2[tid];
  for (int k=0;k<nnz;k++) o += alpha[k]*h2[((size_t)b*Eq + nbr[k])*64 + tid];
  float sv = o, qv = o*o;
  #pragma unroll
  for (int off=1; off<64; off<<=1){ sv += __shfl_xor(sv,off,64); qv += __shfl_xor(qv,off,64); }
  float m = sv*(1.f/64.f);
  float var = qv*(1.f/64.f) - m*m;
  float v = (o-m)*rsqrtf(var+1e-5f)*gam[tid] + bet[tid];
  ent[(size_t)bt*64 + tid] = v>0.f ? v : expm1f(v);
}

// ---------------- relation head: 16-row tiles, swizzled B (grid 768) ----------------
__global__ __launch_bounds__(256) void k_rel(const float* __restrict__ ent, const float* __restrict__ seq,
      const float* __restrict__ rel_emb, const int* __restrict__ ph, const int* __restrict__ pt,
      const int* __restrict__ pr, const unsigned short* __restrict__ Wr1s, const float* __restrict__ br1,
      const float* __restrict__ Wr2, const float* __restrict__ br2, float* __restrict__ out){
  __shared__ unsigned short As[16*936];   // 29,952 B
  unsigned short* Hs = As;                // hidden 16x264 aliased after K-loop
  int tid = threadIdx.x;
  int p0 = blockIdx.x*16;
  for (int idx=tid; idx<16*928; idx+=256){
    int r = idx/928, c = idx - r*928;
    int gp = p0 + r; int b = gp>>8, pp = gp&255;
    float v;
    if (c < 64)      v = ent[((size_t)b*Eq + ph[b*Pq+pp])*64 + c];
    else if (c<128)  v = ent[((size_t)b*Eq + pt[b*Pq+pp])*64 + (c-64)];
    else if (c<160)  v = rel_emb[pr[b*Pq+pp]*32 + (c-128)];
    else             v = seq[(size_t)b*Sq*Hq + (c-160)];
    As[r*936 + c] = f2bf(v);
  }
  __syncthreads();
  int wave = tid>>6, lane = tid&63, m_ = lane&15, kq = lane>>4;
  const f32x4 z = {0.f,0.f,0.f,0.f};
  f32x4 acc[4];
  #pragma unroll
  for (int ct=0;ct<4;ct++) acc[ct]=z;
  const unsigned short* Wb = Wr1s + (size_t)lane*8;
  for (int kb=0; kb<29; kb++){
    int k0 = kb*32;
    s16x8 a0 = *(const s16x8*)&As[m_*936 + k0 + kq*8];
    s16x8 b0 = *(const s16x8*)(Wb + ((size_t)kb*16 + wave*4  )*512);
    s16x8 b1 = *(const s16x8*)(Wb + ((size_t)kb*16 + wave*4+1)*512);
    s16x8 b2 = *(const s16x8*)(Wb + ((size_t)kb*16 + wave*4+2)*512);
    s16x8 b3 = *(const s16x8*)(Wb + ((size_t)kb*16 + wave*4+3)*512);
    acc[0]=MFMA16(a0,b0,acc[0]);
    acc[1]=MFMA16(a0,b1,acc[1]);
    acc[2]=MFMA16(a0,b2,acc[2]);
    acc[3]=MFMA16(a0,b3,acc[3]);
  }
  __syncthreads();
  #pragma unroll
  for (int ct=0;ct<4;ct++){
    int col = wave*64 + ct*16 + m_;
    float bb = br1[col];
    #pragma unroll
    for (int rg=0;rg<4;rg++){
      int row = kq*4 + rg;
      Hs[row*264 + col] = f2bf(fmaxf(acc[ct][rg] + bb, 0.f));
    }
  }
  __syncthreads();
  {
    int r2 = tid>>4, q = tid&15;   // 16 rows x 16 threads
    float p = 0.f;
    for (int u=q*16; u<q*16+16; u++) p += bfu2f(Hs[r2*264+u]) * Wr2[u];
    #pragma unroll
    for (int off=8; off; off>>=1) p += __shfl_down(p, off, 16);
    if (q==0) out[NER_TOT + p0 + r2] = p + br2[0];
  }
}

extern "C" void kernel_launch(void* const* d_in, const int* in_sizes, int n_in,
                              void* d_out, int out_size, void* d_ws, size_t ws_size,
                              hipStream_t stream){
  const float* seq      = (const float*)d_in[0];
  const int*  sstart   = (const int*)d_in[1];
  const int*  slen     = (const int*)d_in[2];
  const int*  etype    = (const int*)d_in[3];
  const int*  ph       = (const int*)d_in[4];
  const int*  pt       = (const int*)d_in[5];
  const int*  pr       = (const int*)d_in[6];
  const float* W_ner1   = (const float*)d_in[7];
  const float* b_ner1   = (const float*)d_in[8];
  const float* W_ner2   = (const float*)d_in[9];
  const float* b_ner2   = (const float*)d_in[10];
  const float* type_emb = (const float*)d_in[11];
  const float* W_g1     = (const float*)d_in[12];
  const float* a_src1   = (const float*)d_in[13];
  const float* a_dst1   = (const float*)d_in[14];
  const float* b_g1     = (const float*)d_in[15];
  const float* g1_gamma = (const float*)d_in[16];
  const float* g1_beta  = (const float*)d_in[17];
  const float* W_g2     = (const float*)d_in[18];
  const float* a_src2   = (const float*)d_in[19];
  const float* a_dst2   = (const float*)d_in[20];
  const float* b_g2     = (const float*)d_in[21];
  const float* g2_gamma = (const float*)d_in[22];
  const float* g2_beta  = (const float*)d_in[23];
  const float* rel_emb  = (const float*)d_in[24];
  const float* W_r1     = (const float*)d_in[25];
  const float* b_r1     = (const float*)d_in[26];
  const float* W_r2     = (const float*)d_in[27];
  const float* b_r2     = (const float*)d_in[28];
  float* outp = (float*)d_out;

  float* x    = (float*)d_ws;                       // 4,718,592 f
  float* g1   = x;                                  // alias: x dead after k_h1
  float* inv  = x   + (size_t)Bq*Eq*Hq;             // 6,144 f
  float* sim  = inv + Bq*Eq;                        // 786,432 f
  float* h2   = sim;                                // alias: sim dead after k_topk
  float* s2   = h2  + (size_t)Bq*Eq*64;             // 6,144 f
  float* d2   = s2  + Bq*Eq;                        // 6,144 f
  float* h1   = sim + (size_t)Bq*Eq*Eq;             // 3,145,728 f
  float* s1   = h1  + (size_t)Bq*Eq*512;            // 24,576 f
  float* d1   = s1  + Bq*Eq*4;                      // 24,576 f
  float* entp = d1  + Bq*Eq*4;                      // 393,216 f
  unsigned char* A = (unsigned char*)(entp + (size_t)Bq*Eq*64);  // 786,432 B
  unsigned short* W1s  = (unsigned short*)(A + (size_t)Bq*Eq*Eq); // 196,608 ush
  unsigned short* W2t  = W1s  + 196608;                           // 4,096 ush
  unsigned short* Wg1s = W2t  + 4096;                             // 393,216 ush
  unsigned short* Wr1s = Wg1s + 393216;                           // 237,568 ush
  // hid (24576x256 bf16) aliases sim+h1 region; dead before k_sim/k_h1 write it.
  unsigned short* hid  = (unsigned short*)sim;

  k_prep<<<3248, 256, 0, stream>>>(W_ner1, W_ner2, W_g1, W_r1, W1s, W2t, Wg1s, Wr1s);
  k_ner1<<<768, 512, 0, stream>>>(seq, W1s, b_ner1, hid);
  k_ner2<<<384, 256, 0, stream>>>(hid, W2t, b_ner2, outp);
  k_span<<<Bq*Eq, 256, 0, stream>>>(seq, sstart, slen, etype, type_emb, x, inv);
  k_sim <<<dim3(4,4,Bq), 256, 0, stream>>>(x, inv, sim);
  k_topk<<<1536, 256, 0, stream>>>(sim, A);
  k_h1  <<<dim3(192,2), 512, 0, stream>>>(x, Wg1s, h1);          // x dead after this
  k_sd1 <<<1536, 256, 0, stream>>>(h1, a_src1, a_dst1, s1, d1);
  k_gat1<<<Bq*Eq, 256, 0, stream>>>(h1, s1, d1, A, b_g1, g1_gamma, g1_beta, g1);
  k_h2  <<<384, 256, 0, stream>>>(g1, W_g2, a_src2, a_dst2, h2, s2, d2);  // sim dead
  k_gat2<<<Bq*Eq, 64, 0, stream>>>(h2, s2, d2, A, b_g2, g2_gamma, g2_beta, entp);
  k_rel <<<768, 256, 0, stream>>>(entp, seq, rel_emb, ph, pt, pr, Wr1s, b_r1, W_r2, b_r2, outp);
}

// Round 12
// 367.225 us; speedup vs baseline: 1.2959x; 1.0405x over previous
//
#include <hip/hip_runtime.h>
#include <hip/hip_bf16.h>
#include <math.h>

#define Bq 48
#define Sq 512
#define Hq 768
#define Eq 128
#define Lq 16
#define Pq 256
#define NERq 11
#define NER_TOT (Bq*Sq*NERq)   // 270336

typedef __attribute__((ext_vector_type(8))) short s16x8;   // 8 bf16 = 4 VGPR
typedef __attribute__((ext_vector_type(4))) float f32x4;
#define MFMA16(a,b,c) __builtin_amdgcn_mfma_f32_16x16x32_bf16(a,b,c,0,0,0)

// f32 -> bf16 bits, round-to-nearest-even
__device__ __forceinline__ unsigned short f2bf(float f){
  union{float f; unsigned u;} v; v.f=f;
  unsigned r = v.u + 0x7fffu + ((v.u>>16)&1u);
  return (unsigned short)(r>>16);
}
__device__ __forceinline__ float bfu2f(unsigned short h){
  union{unsigned u; float f;} c; c.u = ((unsigned)h)<<16; return c.f;
}

// ---------------- prep: weights -> bf16 in MFMA-fragment-contiguous order ----------------
// Layout: Ws[kb][nt][lane][j]  (kb = k0/32, nt = 16-col group, 64 lanes, 8 halves)
// element = W[k = kb*32 + (lane>>4)*8 + j][n = nt*16 + (lane&15)]
__global__ __launch_bounds__(256) void k_prep(const float* __restrict__ W1, const float* __restrict__ W2,
      const float* __restrict__ Wg1, const float* __restrict__ Wr1,
      unsigned short* __restrict__ W1s, unsigned short* __restrict__ W2t,
      unsigned short* __restrict__ Wg1s, unsigned short* __restrict__ Wr1s){
  int i = blockIdx.x*256 + threadIdx.x;   // 831488 total = 3248*256
  if (i < 196608){            // W1s: N=256 (NT=16), K=768 (24 kb)
    int j = i&7, lane = (i>>3)&63, rem = i>>9;
    int nt = rem&15, kb = rem>>4;
    int k = kb*32 + (lane>>4)*8 + j, n = nt*16 + (lane&15);
    W1s[i] = f2bf(W1[k*256 + n]);
  } else if (i < 200704){     // W2t: 16x256, rows 11..15 zero
    int j = i - 196608; int n = j>>8, k = j&255;
    W2t[j] = (n < NERq) ? f2bf(W2[k*NERq + n]) : 0;
  } else if (i < 593920){     // Wg1s: N=512 (NT=32), K=768 (24 kb)
    int q = i - 200704;
    int j = q&7, lane = (q>>3)&63, rem = q>>9;
    int nt = rem&31, kb = rem>>5;
    int k = kb*32 + (lane>>4)*8 + j, n = nt*16 + (lane&15);
    Wg1s[q] = f2bf(Wg1[k*512 + n]);
  } else {                    // Wr1s: N=256 (NT=16), K=928 (29 kb)
    int q = i - 593920;
    int j = q&7, lane = (q>>3)&63, rem = q>>9;
    int nt = rem&15, kb = rem>>4;
    int k = kb*32 + (lane>>4)*8 + j, n = nt*16 + (lane&15);
    Wr1s[q] = f2bf(Wr1[k*256 + n]);
  }
}

// ---------------- NER layer 1: 8-wave blocks, LDS A-tile, coalesced swizzled B ----------------
__global__ __launch_bounds__(512) void k_ner1(const float* __restrict__ seq, const unsigned short* __restrict__ W1s,
      const float* __restrict__ b1, unsigned short* __restrict__ hid){
  __shared__ unsigned short As[32*776];   // 48.4KB -> 3 blocks/CU, 24 waves/CU
  int tid = threadIdx.x;
  size_t row0 = (size_t)blockIdx.x*32;
  const float4* src = (const float4*)(seq + row0*Hq);
  for (int v=tid; v<6144; v+=512){
    float4 f = src[v];
    int r = v/192, k = (v - r*192)*4;
    ushort4 h = { f2bf(f.x), f2bf(f.y), f2bf(f.z), f2bf(f.w) };
    *(ushort4*)&As[r*776 + k] = h;
  }
  __syncthreads();
  int wave = tid>>6, lane = tid&63, m_ = lane&15, kq = lane>>4;
  const f32x4 z = {0.f,0.f,0.f,0.f};
  f32x4 acc[2][2];
  acc[0][0]=z; acc[0][1]=z; acc[1][0]=z; acc[1][1]=z;
  const unsigned short* Wb = W1s + (size_t)lane*8;
  for (int kb=0; kb<24; kb++){
    int k0 = kb*32;
    s16x8 a0 = *(const s16x8*)&As[m_*776 + k0 + kq*8];
    s16x8 a1 = *(const s16x8*)&As[(16+m_)*776 + k0 + kq*8];
    s16x8 b0 = *(const s16x8*)(Wb + ((size_t)kb*16 + 2*wave  )*512);
    s16x8 b1 = *(const s16x8*)(Wb + ((size_t)kb*16 + 2*wave+1)*512);
    acc[0][0]=MFMA16(a0,b0,acc[0][0]); acc[1][0]=MFMA16(a1,b0,acc[1][0]);
    acc[0][1]=MFMA16(a0,b1,acc[0][1]); acc[1][1]=MFMA16(a1,b1,acc[1][1]);
  }
  #pragma unroll
  for (int ct=0;ct<2;ct++){
    int col = wave*32 + ct*16 + m_;
    float bb = b1[col];
    #pragma unroll
    for (int rt=0;rt<2;rt++)
      #pragma unroll
      for (int rg=0;rg<4;rg++){
        int row = rt*16 + kq*4 + rg;
        hid[(row0+row)*256 + col] = f2bf(fmaxf(acc[rt][ct][rg] + bb, 0.f));
      }
  }
}

// ---------------- NER layer 2: hidden(bf16) @ W2t, K=256; 4-wave blocks ----------------
__global__ __launch_bounds__(256) void k_ner2(const unsigned short* __restrict__ hid,
      const unsigned short* __restrict__ W2t, const float* __restrict__ b2, float* __restrict__ out){
  int tid = threadIdx.x, wave = tid>>6, lane = tid&63, m_ = lane&15, kq = lane>>4;
  size_t row0 = (size_t)blockIdx.x*64 + wave*16;   // 384 blocks
  f32x4 a2 = {0.f,0.f,0.f,0.f};
  for (int k0=0;k0<256;k0+=32){
    s16x8 a = *(const s16x8*)&hid[(row0+m_)*256 + k0 + kq*8];
    s16x8 b = *(const s16x8*)&W2t[m_*256 + k0 + kq*8];
    a2 = MFMA16(a,b,a2);
  }
  if (m_ < NERq){
    float bb = b2[m_];
    #pragma unroll
    for (int rg=0;rg<4;rg++)
      out[(row0+kq*4+rg)*NERq + m_] = a2[rg] + bb;
  }
}

// ---------------- span pooling: register-staged tokens ----------------
__global__ __launch_bounds__(256) void k_span(const float* __restrict__ seq, const int* __restrict__ sstart,
      const int* __restrict__ slen, const int* __restrict__ etype, const float* __restrict__ type_emb,
      float* __restrict__ x, float* __restrict__ inv){
  __shared__ float red16[4][16];
  __shared__ float wv[16];
  __shared__ float redn[4];
  int be = blockIdx.x;
  int b = be >> 7;
  int tid = threadIdx.x;
  int wave = tid>>6, lane = tid&63;
  int st = sstart[be], ln = slen[be];
  int cnt = ln + 1;                // mask = pos <= len; rows >= cnt have weight exactly 0
  const float* base = seq + ((size_t)b*Sq + st)*Hq;
  float tokr[16][3];
  #pragma unroll
  for (int l=0;l<16;l++){
    if (l < cnt){
      tokr[l][0] = base[l*768 + tid];
      tokr[l][1] = base[l*768 + tid + 256];
      tokr[l][2] = base[l*768 + tid + 512];
    } else {
      tokr[l][0]=0.f; tokr[l][1]=0.f; tokr[l][2]=0.f;
    }
  }
  float meanr[3];
  #pragma unroll
  for (int c=0;c<3;c++){
    float s=0.f;
    #pragma unroll
    for (int l=0;l<16;l++) if (l < cnt) s += tokr[l][c];
    meanr[c] = s/(float)cnt;
  }
  #pragma unroll
  for (int l=0;l<16;l++){
    if (l < cnt){
      float p = tokr[l][0]*meanr[0] + tokr[l][1]*meanr[1] + tokr[l][2]*meanr[2];
      #pragma unroll
      for (int off=32; off; off>>=1) p += __shfl_down(p, off, 64);
      if (lane==0) red16[wave][l] = p;
    }
  }
  __syncthreads();
  if (tid==0){
    float sc[16];
    for (int l=0;l<cnt;l++) sc[l] = red16[0][l]+red16[1][l]+red16[2][l]+red16[3][l];
    float m=-1e30f;
    for (int l=0;l<cnt;l++) m = fmaxf(m, sc[l]);
    float ssum=0.f;
    float e[16];
    for (int l=0;l<16;l++){
      e[l] = (l<cnt) ? expf(sc[l]-m) : 0.f;
      ssum += e[l];
    }
    float rs = 1.f/ssum;
    for (int l=0;l<16;l++) wv[l] = e[l]*rs;
  }
  __syncthreads();
  const float* te = type_emb + (size_t)etype[be]*Hq;
  float nrm = 0.f;
  #pragma unroll
  for (int c=0;c<3;c++){
    int h = tid + c*256;
    float p=0.f;
    #pragma unroll
    for (int l=0;l<16;l++) if (l < cnt) p += wv[l]*tokr[l][c];
    float xv = p + te[h];
    x[(size_t)be*Hq + h] = xv;
    nrm += xv*xv;
  }
  #pragma unroll
  for (int off=32; off; off>>=1) nrm += __shfl_down(nrm, off, 64);
  if (lane==0) redn[wave]=nrm;
  __syncthreads();
  if (tid==0){
    float t = redn[0]+redn[1]+redn[2]+redn[3];
    inv[be] = 1.f/fmaxf(sqrtf(t), 1e-12f);
  }
}

// ---------------- sim: 32x32 tiles, row-major LDS, float4 reads (bit-identical chain) ----------------
__global__ __launch_bounds__(256) void k_sim(const float* __restrict__ x, const float* __restrict__ inv,
                                             float* __restrict__ sim){
  __shared__ float As[32][132];   // row-major; stride 132 f32 (16B-aligned rows)
  __shared__ float Bs[32][132];
  int b = blockIdx.z;
  int i0 = blockIdx.y*32, j0 = blockIdx.x*32;
  int tid = threadIdx.x;
  int ty = tid>>4, tx = tid&15;   // thread tile: rows i0+ty*2+{0,1}, cols j0+tx*2+{0,1}
  float acc[2][2] = {{0.f,0.f},{0.f,0.f}};
  const float* xb = x + (size_t)b*Eq*Hq;
  for (int k0=0;k0<768;k0+=128){
    // stage: direct float4 copy (coalesced global b128 -> sequential LDS b128)
    for (int idx=tid; idx<1024; idx+=256){
      int r = idx>>5, kq = idx&31;
      *(float4*)&As[r][kq*4] = *(const float4*)&xb[(size_t)(i0+r)*768 + k0 + kq*4];
      *(float4*)&Bs[r][kq*4] = *(const float4*)&xb[(size_t)(j0+r)*768 + k0 + kq*4];
    }
    __syncthreads();
    for (int kk4=0;kk4<32;kk4++){
      float4 a0 = *(const float4*)&As[ty*2  ][kk4*4];
      float4 a1 = *(const float4*)&As[ty*2+1][kk4*4];
      float4 b0 = *(const float4*)&Bs[tx*2  ][kk4*4];
      float4 b1 = *(const float4*)&Bs[tx*2+1][kk4*4];
      // per-acc chains ascending in k (x,y,z,w = k0+kk4*4+0..3) -> bit-identical
      acc[0][0]=fmaf(a0.x,b0.x,acc[0][0]); acc[0][0]=fmaf(a0.y,b0.y,acc[0][0]);
      acc[0][0]=fmaf(a0.z,b0.z,acc[0][0]); acc[0][0]=fmaf(a0.w,b0.w,acc[0][0]);
      acc[0][1]=fmaf(a0.x,b1.x,acc[0][1]); acc[0][1]=fmaf(a0.y,b1.y,acc[0][1]);
      acc[0][1]=fmaf(a0.z,b1.z,acc[0][1]); acc[0][1]=fmaf(a0.w,b1.w,acc[0][1]);
      acc[1][0]=fmaf(a1.x,b0.x,acc[1][0]); acc[1][0]=fmaf(a1.y,b0.y,acc[1][0]);
      acc[1][0]=fmaf(a1.z,b0.z,acc[1][0]); acc[1][0]=fmaf(a1.w,b0.w,acc[1][0]);
      acc[1][1]=fmaf(a1.x,b1.x,acc[1][1]); acc[1][1]=fmaf(a1.y,b1.y,acc[1][1]);
      acc[1][1]=fmaf(a1.z,b1.z,acc[1][1]); acc[1][1]=fmaf(a1.w,b1.w,acc[1][1]);
    }
    __syncthreads();
  }
  float invi[2], invj[2];
  invi[0]=inv[b*Eq + i0+ty*2]; invi[1]=inv[b*Eq + i0+ty*2+1];
  invj[0]=inv[b*Eq + j0+tx*2]; invj[1]=inv[b*Eq + j0+tx*2+1];
  float* sb = sim + (size_t)b*Eq*Eq;
  #pragma unroll
  for (int r=0;r<2;r++)
    #pragma unroll
    for (int c=0;c<2;c++)
      sb[(size_t)(i0+ty*2+r)*Eq + j0+tx*2+c] = acc[r][c]*invi[r]*invj[c];
}

// ---------------- top-6 per row: one wave per row (4 rows/block, 1536 blocks) ----------------
__global__ __launch_bounds__(256) void k_topk(const float* __restrict__ sim, unsigned char* __restrict__ A){
  int row = blockIdx.x*4 + (threadIdx.x>>6);
  int lane = threadIdx.x & 63;
  int b = row>>7, i = row&127;
  const float* r = sim + (size_t)b*Eq*Eq + (size_t)i*Eq;
  float x0 = r[lane], x1 = r[64+lane];
  unsigned char a0=0, a1=0;
  #pragma unroll
  for (int k=0;k<6;k++){
    float m; int idx;
    if (x0 >= x1){ m=x0; idx=lane; } else { m=x1; idx=64+lane; }
    #pragma unroll
    for (int off=32; off; off>>=1){
      float om = __shfl_xor(m, off, 64);
      int oi = __shfl_xor(idx, off, 64);
      if (om > m || (om == m && oi < idx)){ m = om; idx = oi; }
    }
    if (m > 0.1f && idx != i){
      if (idx == lane) a0 = 1;
      if (idx == 64+lane) a1 = 1;
    }
    if (idx == lane) x0 = -1e30f;
    if (idx == 64+lane) x1 = -1e30f;
  }
  if (lane == i) a0 = 1;
  if (64+lane == i) a1 = 1;
  unsigned char* Ar = A + (size_t)b*Eq*Eq + (size_t)i*Eq;
  Ar[lane] = a0; Ar[64+lane] = a1;
}

// ---------------- h1 = x @ W_g1 (768->512): 8-wave blocks, LDS A-tile, swizzled B ----------------
__global__ __launch_bounds__(512) void k_h1(const float* __restrict__ x, const unsigned short* __restrict__ Wg1s,
                                            float* __restrict__ h1){
  __shared__ unsigned short As[32*776];
  int tid = threadIdx.x;
  size_t row0 = (size_t)blockIdx.x*32;
  const float4* src = (const float4*)(x + row0*Hq);
  for (int v=tid; v<6144; v+=512){
    float4 f = src[v];
    int r = v/192, k = (v - r*192)*4;
    ushort4 h = { f2bf(f.x), f2bf(f.y), f2bf(f.z), f2bf(f.w) };
    *(ushort4*)&As[r*776 + k] = h;
  }
  __syncthreads();
  int wave = tid>>6, lane = tid&63, m_ = lane&15, kq = lane>>4;
  int ntb = blockIdx.y*16 + 2*wave;      // nt group base (NT=32 total)
  const f32x4 z = {0.f,0.f,0.f,0.f};
  f32x4 acc[2][2];
  acc[0][0]=z; acc[0][1]=z; acc[1][0]=z; acc[1][1]=z;
  const unsigned short* Wb = Wg1s + (size_t)lane*8;
  for (int kb=0; kb<24; kb++){
    int k0 = kb*32;
    s16x8 a0 = *(const s16x8*)&As[m_*776 + k0 + kq*8];
    s16x8 a1 = *(const s16x8*)&As[(16+m_)*776 + k0 + kq*8];
    s16x8 b0 = *(const s16x8*)(Wb + ((size_t)kb*32 + ntb  )*512);
    s16x8 b1 = *(const s16x8*)(Wb + ((size_t)kb*32 + ntb+1)*512);
    acc[0][0]=MFMA16(a0,b0,acc[0][0]); acc[1][0]=MFMA16(a1,b0,acc[1][0]);
    acc[0][1]=MFMA16(a0,b1,acc[0][1]); acc[1][1]=MFMA16(a1,b1,acc[1][1]);
  }
  #pragma unroll
  for (int ct=0;ct<2;ct++){
    int col = (ntb+ct)*16 + m_;
    #pragma unroll
    for (int rt=0;rt<2;rt++)
      #pragma unroll
      for (int rg=0;rg<4;rg++){
        int row = rt*16 + kq*4 + rg;
        h1[(row0+row)*512 + col] = acc[rt][ct][rg];
      }
  }
}

// ---------------- s1,d1 attention scores ----------------
__global__ __launch_bounds__(256) void k_sd1(const float* __restrict__ h1, const float* __restrict__ as1,
      const float* __restrict__ ad1, float* __restrict__ s1, float* __restrict__ d1){
  int gw = (blockIdx.x*256 + threadIdx.x)>>6;
  int lane = threadIdx.x & 63;
  if (gw >= Bq*Eq) return;
  const float* hr = h1 + (size_t)gw*512;
  int hd = lane>>4;
  int i0 = lane*8;
  float4 va = *(const float4*)&hr[i0];
  float4 vb = *(const float4*)&hr[i0+4];
  float av[8] = {va.x,va.y,va.z,va.w,vb.x,vb.y,vb.z,vb.w};
  float ps=0.f, pd=0.f;
  #pragma unroll
  for (int u=0;u<8;u++){
    ps += av[u]*as1[i0+u];
    pd += av[u]*ad1[i0+u];
  }
  #pragma unroll
  for (int off=8; off; off>>=1){ ps += __shfl_down(ps,off,16); pd += __shfl_down(pd,off,16); }
  if ((lane&15)==0){ s1[(size_t)gw*4+hd]=ps; d1[(size_t)gw*4+hd]=pd; }
}

// ---------------- GAT1 ----------------
__global__ __launch_bounds__(256) void k_gat1(const float* __restrict__ h1, const float* __restrict__ s1,
      const float* __restrict__ d1, const unsigned char* __restrict__ A,
      const float* __restrict__ bg1, const float* __restrict__ gam, const float* __restrict__ bet,
      float* __restrict__ g1){
  __shared__ float alpha[4][128];
  __shared__ int nbr[128];
  __shared__ int nnz_s;
  __shared__ float outv[512];
  __shared__ float red[8];
  __shared__ float mv_s, rstd_s;
  int bt = blockIdx.x; int b = bt>>7, t = bt&127;
  int tid = threadIdx.x;
  if (tid==0) nnz_s = 0;
  __syncthreads();
  const unsigned char* Ab = A + (size_t)b*Eq*Eq;
  if (tid < 128){
    if (Ab[(size_t)tid*Eq + t]){ int p = atomicAdd(&nnz_s, 1); nbr[p] = tid; }
  }
  __syncthreads();
  int nnz = nnz_s;
  for (int idx=tid; idx<nnz*4; idx+=256){
    int k = idx>>2, hd = idx&3;
    int s = nbr[k];
    float ev = s1[(size_t)(b*Eq+s)*4 + hd] + d1[(size_t)bt*4 + hd];
    alpha[hd][k] = ev>0.f ? ev : 0.2f*ev;
  }
  __syncthreads();
  if (tid < 4){
    float m = -1e30f;
    for (int k=0;k<nnz;k++) m = fmaxf(m, alpha[tid][k]);
    float ss = 0.f;
    for (int k=0;k<nnz;k++){ float e = expf(alpha[tid][k]-m); alpha[tid][k]=e; ss+=e; }
    float rs = 1.f/ss;
    for (int k=0;k<nnz;k++) alpha[tid][k] *= rs;
  }
  __syncthreads();
  for (int c=tid; c<512; c+=256){
    int hd = c>>7;
    float o = 0.f;
    for (int k=0;k<nnz;k++) o += alpha[hd][k] * h1[((size_t)b*Eq + nbr[k])*512 + c];
    outv[c] = o + bg1[c];
  }
  __syncthreads();
  float ls=0.f, lq=0.f;
  for (int c=tid;c<512;c+=256){ float v=outv[c]; ls+=v; lq+=v*v; }
  #pragma unroll
  for (int off=32; off; off>>=1){ ls += __shfl_down(ls,off,64); lq += __shfl_down(lq,off,64); }
  int wv_ = tid>>6;
  if ((tid&63)==0){ red[wv_]=ls; red[4+wv_]=lq; }
  __syncthreads();
  if (tid==0){
    float sm=red[0]+red[1]+red[2]+red[3], sq=red[4]+red[5]+red[6]+red[7];
    float m = sm/512.f; mv_s = m; rstd_s = rsqrtf(sq/512.f - m*m + 1e-5f);
  }
  __syncthreads();
  for (int c=tid;c<512;c+=256){
    float v = (outv[c]-mv_s)*rstd_s*gam[c] + bet[c];
    g1[(size_t)bt*512 + c] = v>0.f ? v : expm1f(v);
  }
}

// ---------------- h2 = g1 @ W_g2 (512->64) + s2,d2 ----------------
__global__ __launch_bounds__(256) void k_h2(const float* __restrict__ g1, const float* __restrict__ Wg2,
      const float* __restrict__ as2, const float* __restrict__ ad2,
      float* __restrict__ h2, float* __restrict__ s2, float* __restrict__ d2){
  __shared__ float gt[16*512];
  int tid=threadIdx.x;
  size_t row0 = (size_t)blockIdx.x*16;
  const float4* src = (const float4*)(g1 + row0*512);
  for (int v=tid; v<2048; v+=256) *(float4*)&gt[v*4] = src[v];
  __syncthreads();
  int w = tid>>6, lane = tid&63;
  float acc[4];
  #pragma unroll
  for (int r=0;r<4;r++) acc[r]=0.f;
  for (int k=0;k<512;k+=4){
    float w0=Wg2[(k+0)*64+lane];
    float w1=Wg2[(k+1)*64+lane];
    float w2=Wg2[(k+2)*64+lane];
    float w3=Wg2[(k+3)*64+lane];
    #pragma unroll
    for (int r=0;r<4;r++){
      const float4 t = *(const float4*)&gt[(w*4+r)*512 + k];
      acc[r]=fmaf(t.x,w0,acc[r]);
      acc[r]=fmaf(t.y,w1,acc[r]);
      acc[r]=fmaf(t.z,w2,acc[r]);
      acc[r]=fmaf(t.w,w3,acc[r]);
    }
  }
  float as_=as2[lane], ad_=ad2[lane];
  #pragma unroll
  for (int r=0;r<4;r++){
    size_t row = row0 + w*4 + r;
    h2[row*64 + lane] = acc[r];
    float ps = acc[r]*as_, pd = acc[r]*ad_;
    #pragma unroll
    for (int off=32; off; off>>=1){ ps += __shfl_down(ps,off,64); pd += __shfl_down(pd,off,64); }
    if (lane==0){ s2[row]=ps; d2[row]=pd; }
  }
}

// ---------------- GAT2 ----------------
__global__ __launch_bounds__(64) void k_gat2(const float* __restrict__ h2, const float* __restrict__ s2,
      const float* __restrict__ d2, const unsigned char* __restrict__ A,
      const float* __restrict__ bg2, const float* __restrict__ gam, const float* __restrict__ bet,
      float* __restrict__ ent){
  __shared__ float alpha[128];
  __shared__ int nbr[128];
  __shared__ int nnz_s;
  int bt = blockIdx.x; int b = bt>>7, t = bt&127;
  int tid=threadIdx.x;
  if (tid==0) nnz_s=0;
  __syncthreads();
  const unsigned char* Ab = A + (size_t)b*Eq*Eq;
  for (int s=tid; s<128; s+=64) if (Ab[(size_t)s*Eq + t]) { int p=atomicAdd(&nnz_s,1); nbr[p]=s; }
  __syncthreads();
  int nnz = nnz_s;
  float dt = d2[bt];
  for (int k=tid; k<nnz; k+=64){
    float ev = s2[(size_t)b*Eq + nbr[k]] + dt;
    alpha[k] = ev>0.f ? ev : 0.2f*ev;
  }
  __syncthreads();
  if (tid==0){
    float m=-1e30f;
    for (int k=0;k<nnz;k++) m = fmaxf(m, alpha[k]);
    float ss=0.f;
    for (int k=0;k<nnz;k++){ float e=expf(alpha[k]-m); alpha[k]=e; ss+=e; }
    float rs=1.f/ss;
    for (int k=0;k<nnz;k++) alpha[k]*=rs;
  }
  __syncthreads();
  float o = bg2[tid];
  for (int k=0;k<nnz;k++) o += alpha[k]*h2[((size_t)b*Eq + nbr[k])*64 + tid];
  float sv = o, qv = o*o;
  #pragma unroll
  for (int off=1; off<64; off<<=1){ sv += __shfl_xor(sv,off,64); qv += __shfl_xor(qv,off,64); }
  float m = sv*(1.f/64.f);
  float var = qv*(1.f/64.f) - m*m;
  float v = (o-m)*rsqrtf(var+1e-5f)*gam[tid] + bet[tid];
  ent[(size_t)bt*64 + tid] = v>0.f ? v : expm1f(v);
}

// ---------------- relation head: 16-row tiles, swizzled B (grid 768) ----------------
__global__ __launch_bounds__(256) void k_rel(const float* __restrict__ ent, const float* __restrict__ seq,
      const float* __restrict__ rel_emb, const int* __restrict__ ph, const int* __restrict__ pt,
      const int* __restrict__ pr, const unsigned short* __restrict__ Wr1s, const float* __restrict__ br1,
      const float* __restrict__ Wr2, const float* __restrict__ br2, float* __restrict__ out){
  __shared__ unsigned short As[16*936];   // 29,952 B
  unsigned short* Hs = As;                // hidden 16x264 aliased after K-loop
  int tid = threadIdx.x;
  int p0 = blockIdx.x*16;
  for (int idx=tid; idx<16*928; idx+=256){
    int r = idx/928, c = idx - r*928;
    int gp = p0 + r; int b = gp>>8, pp = gp&255;
    float v;
    if (c < 64)      v = ent[((size_t)b*Eq + ph[b*Pq+pp])*64 + c];
    else if (c<128)  v = ent[((size_t)b*Eq + pt[b*Pq+pp])*64 + (c-64)];
    else if (c<160)  v = rel_emb[pr[b*Pq+pp]*32 + (c-128)];
    else             v = seq[(size_t)b*Sq*Hq + (c-160)];
    As[r*936 + c] = f2bf(v);
  }
  __syncthreads();
  int wave = tid>>6, lane = tid&63, m_ = lane&15, kq = lane>>4;
  const f32x4 z = {0.f,0.f,0.f,0.f};
  f32x4 acc[4];
  #pragma unroll
  for (int ct=0;ct<4;ct++) acc[ct]=z;
  const unsigned short* Wb = Wr1s + (size_t)lane*8;
  for (int kb=0; kb<29; kb++){
    int k0 = kb*32;
    s16x8 a0 = *(const s16x8*)&As[m_*936 + k0 + kq*8];
    s16x8 b0 = *(const s16x8*)(Wb + ((size_t)kb*16 + wave*4  )*512);
    s16x8 b1 = *(const s16x8*)(Wb + ((size_t)kb*16 + wave*4+1)*512);
    s16x8 b2 = *(const s16x8*)(Wb + ((size_t)kb*16 + wave*4+2)*512);
    s16x8 b3 = *(const s16x8*)(Wb + ((size_t)kb*16 + wave*4+3)*512);
    acc[0]=MFMA16(a0,b0,acc[0]);
    acc[1]=MFMA16(a0,b1,acc[1]);
    acc[2]=MFMA16(a0,b2,acc[2]);
    acc[3]=MFMA16(a0,b3,acc[3]);
  }
  __syncthreads();
  #pragma unroll
  for (int ct=0;ct<4;ct++){
    int col = wave*64 + ct*16 + m_;
    float bb = br1[col];
    #pragma unroll
    for (int rg=0;rg<4;rg++){
      int row = kq*4 + rg;
      Hs[row*264 + col] = f2bf(fmaxf(acc[ct][rg] + bb, 0.f));
    }
  }
  __syncthreads();
  {
    int r2 = tid>>4, q = tid&15;   // 16 rows x 16 threads
    float p = 0.f;
    for (int u=q*16; u<q*16+16; u++) p += bfu2f(Hs[r2*264+u]) * Wr2[u];
    #pragma unroll
    for (int off=8; off; off>>=1) p += __shfl_down(p, off, 16);
    if (q==0) out[NER_TOT + p0 + r2] = p + br2[0];
  }
}

extern "C" void kernel_launch(void* const* d_in, const int* in_sizes, int n_in,
                              void* d_out, int out_size, void* d_ws, size_t ws_size,
                              hipStream_t stream){
  const float* seq      = (const float*)d_in[0];
  const int*  sstart   = (const int*)d_in[1];
  const int*  slen     = (const int*)d_in[2];
  const int*  etype    = (const int*)d_in[3];
  const int*  ph       = (const int*)d_in[4];
  const int*  pt       = (const int*)d_in[5];
  const int*  pr       = (const int*)d_in[6];
  const float* W_ner1   = (const float*)d_in[7];
  const float* b_ner1   = (const float*)d_in[8];
  const float* W_ner2   = (const float*)d_in[9];
  const float* b_ner2   = (const float*)d_in[10];
  const float* type_emb = (const float*)d_in[11];
  const float* W_g1     = (const float*)d_in[12];
  const float* a_src1   = (const float*)d_in[13];
  const float* a_dst1   = (const float*)d_in[14];
  const float* b_g1     = (const float*)d_in[15];
  const float* g1_gamma = (const float*)d_in[16];
  const float* g1_beta  = (const float*)d_in[17];
  const float* W_g2     = (const float*)d_in[18];
  const float* a_src2   = (const float*)d_in[19];
  const float* a_dst2   = (const float*)d_in[20];
  const float* b_g2     = (const float*)d_in[21];
  const float* g2_gamma = (const float*)d_in[22];
  const float* g2_beta  = (const float*)d_in[23];
  const float* rel_emb  = (const float*)d_in[24];
  const float* W_r1     = (const float*)d_in[25];
  const float* b_r1     = (const float*)d_in[26];
  const float* W_r2     = (const float*)d_in[27];
  const float* b_r2     = (const float*)d_in[28];
  float* outp = (float*)d_out;

  float* x    = (float*)d_ws;                       // 4,718,592 f
  float* g1   = x;                                  // alias: x dead after k_h1
  float* inv  = x   + (size_t)Bq*Eq*Hq;             // 6,144 f
  float* sim  = inv + Bq*Eq;                        // 786,432 f
  float* h2   = sim;                                // alias: sim dead after k_topk
  float* s2   = h2  + (size_t)Bq*Eq*64;             // 6,144 f
  float* d2   = s2  + Bq*Eq;                        // 6,144 f
  float* h1   = sim + (size_t)Bq*Eq*Eq;             // 3,145,728 f
  float* s1   = h1  + (size_t)Bq*Eq*512;            // 24,576 f
  float* d1   = s1  + Bq*Eq*4;                      // 24,576 f
  float* entp = d1  + Bq*Eq*4;                      // 393,216 f
  unsigned char* A = (unsigned char*)(entp + (size_t)Bq*Eq*64);  // 786,432 B
  unsigned short* W1s  = (unsigned short*)(A + (size_t)Bq*Eq*Eq); // 196,608 ush
  unsigned short* W2t  = W1s  + 196608;                           // 4,096 ush
  unsigned short* Wg1s = W2t  + 4096;                             // 393,216 ush
  unsigned short* Wr1s = Wg1s + 393216;                           // 237,568 ush
  // hid (24576x256 bf16) aliases sim+h1 region; dead before k_sim/k_h1 write it.
  unsigned short* hid  = (unsigned short*)sim;

  k_prep<<<3248, 256, 0, stream>>>(W_ner1, W_ner2, W_g1, W_r1, W1s, W2t, Wg1s, Wr1s);
  k_ner1<<<768, 512, 0, stream>>>(seq, W1s, b_ner1, hid);
  k_ner2<<<384, 256, 0, stream>>>(hid, W2t, b_ner2, outp);
  k_span<<<Bq*Eq, 256, 0, stream>>>(seq, sstart, slen, etype, type_emb, x, inv);
  k_sim <<<dim3(4,4,Bq), 256, 0, stream>>>(x, inv, sim);
  k_topk<<<1536, 256, 0, stream>>>(sim, A);
  k_h1  <<<dim3(192,2), 512, 0, stream>>>(x, Wg1s, h1);          // x dead after this
  k_sd1 <<<1536, 256, 0, stream>>>(h1, a_src1, a_dst1, s1, d1);
  k_gat1<<<Bq*Eq, 256, 0, stream>>>(h1, s1, d1, A, b_g1, g1_gamma, g1_beta, g1);
  k_h2  <<<384, 256, 0, stream>>>(g1, W_g2, a_src2, a_dst2, h2, s2, d2);  // sim dead
  k_gat2<<<Bq*Eq, 64, 0, stream>>>(h2, s2, d2, A, b_g2, g2_gamma, g2_beta, entp);
  k_rel <<<768, 256, 0, stream>>>(entp, seq, rel_emb, ph, pt, pr, Wr1s, b_r1, W_r2, b_r2, outp);
}